// Round 1
// 85.041 us; speedup vs baseline: 1.0054x; 1.0054x over previous
//
#include <hip/hip_runtime.h>

// AttentionBasedPooling: B=2048, F=32 (P=496 pairs), D=64, H=64.
// afm[b] = sum_p attn[b,p] * dot(x_i,x_j); attn = softmax_p of
// scores[p] = relu((x_i*x_j)@W1 + b1)@Ws + bs.
//
// v2: two-kernel launch. prep_kernel (1 block) packs into d_ws:
//   [0,      8192)  W1^T A-fragments, per-lane layout: f16x8 @ ((nt*2+ks)*64+lane)
//   [8192,  16384)  (b1,Ws) per-lane pairs: float4 {b1[n0],Ws[n0],b1[n1],Ws[n1]}
//   [16384, 18432)  pair table: (i_off<<16)|j_off byte offsets into xs
// This replaces the old 96-scalar-global-load prologue (the register-pressure
// peak that forced scratch spills under the 128-VGPR launch_bounds cap) with
// 17 wide vector loads whose destinations ARE the steady-state arrays.
// MFMA datapath unchanged from the verified version: D = W1^T-frag (A) x
// cross-frag (B) = h^T via mfma_f32_16x16x32_f16; ones-row A fragment gives
// s_p at row0 reg0.

#define F 32
#define D 64
#define H 64
#define P 496
#define NT 4
#define MT 32   // padded; tile 31 is dummy (writes scores[496..511], never read)
#define RB 72   // f16 per xs row: 64 + 8 pad -> 144 B row stride

typedef __attribute__((ext_vector_type(8))) _Float16 f16x8;
typedef __attribute__((ext_vector_type(2))) _Float16 f16x2;
typedef __attribute__((ext_vector_type(4))) float f32x4;

__global__ __launch_bounds__(256) void prep_kernel(
    const float* __restrict__ W1, const float* __restrict__ b1,
    const float* __restrict__ Ws, char* __restrict__ ws)
{
    const int tid  = threadIdx.x;
    const int lane = tid & 63;
    const int w    = tid >> 6;        // doubles as nt
    const int l15  = lane & 15;
    const int quad = lane >> 4;

    // W1^T A-fragments: frag[nt][ks][j8] = W1[(quad*8+j8+32ks)*H + nt*16+l15]
    f16x8* wtab = (f16x8*)ws;
    #pragma unroll
    for (int ks = 0; ks < 2; ++ks) {
        f16x8 v;
        #pragma unroll
        for (int j8 = 0; j8 < 8; ++j8) {
            int k = quad * 8 + j8 + ks * 32;
            v[j8] = (_Float16)W1[k * H + w * 16 + l15];
        }
        wtab[(w * 2 + ks) * 64 + lane] = v;
    }

    // (b1,Ws) pairs: i = nt*4+reg -> n = (i>>2)*16 + quad*4 + (i&3)
    float4* bwtab = (float4*)(ws + 8192);
    #pragma unroll
    for (int ii = w * 2; ii < w * 2 + 2; ++ii) {
        int i0 = ii * 2, i1 = ii * 2 + 1;
        int n0 = (i0 >> 2) * 16 + quad * 4 + (i0 & 3);
        int n1 = (i1 >> 2) * 16 + quad * 4 + (i1 & 3);
        bwtab[ii * 64 + lane] = make_float4(b1[n0], Ws[n0], b1[n1], Ws[n1]);
    }

    // pair table, closed form (exact at boundaries; one-step correction)
    int* ptab = (int*)(ws + 16384);
    for (int p = tid; p < 512; p += 256) {
        int i, j;
        if (p < P) {
            i = (int)((63.0f - __builtin_sqrtf((float)(3969 - 8 * p))) * 0.5f);
            if (i * (63 - i) / 2 > p) --i;
            if ((i + 1) * (62 - i) / 2 <= p) ++i;
            j = i + 1 + (p - i * (63 - i) / 2);
        } else { i = 0; j = 0; }
        ptab[p] = (i * RB * 2) << 16 | (j * RB * 2);
    }
}

__global__ __launch_bounds__(256, 4) void afm_kernel(
    const float* __restrict__ x, const float* __restrict__ bs,
    const char* __restrict__ ws, float* __restrict__ out)
{
    __shared__ _Float16 xs[F * RB];       // f16 x-tile
    __shared__ float scores[512];
    __shared__ float svals[512];
    __shared__ float redmax[4], rednum[4], redden[4];

    const int tid  = threadIdx.x;
    const int b    = blockIdx.x;
    const int lane = tid & 63;
    const int wid  = tid >> 6;
    const int l15  = lane & 15;
    const int quad = lane >> 4;

    // ---- stage x[b] -> f16 LDS (coalesced float4 reads) ----
    const float4* xb4 = (const float4*)(x + (size_t)b * (F * D));
    #pragma unroll
    for (int it = 0; it < 2; ++it) {
        int v = tid + it * 256;
        float4 wv = xb4[v];
        int row = v >> 4, col = (v & 15) * 4;
        f16x2 lo = { (_Float16)wv.x, (_Float16)wv.y };
        f16x2 hi = { (_Float16)wv.z, (_Float16)wv.w };
        *(f16x2*)&xs[row * RB + col]     = lo;
        *(f16x2*)&xs[row * RB + col + 2] = hi;
    }

    // ---- vector-load prepacked tables (L2-resident, per-lane layout) ----
    const f16x8* wt = (const f16x8*)ws;
    f16x8 wfrag[NT][2];
    #pragma unroll
    for (int nt = 0; nt < NT; ++nt)
        #pragma unroll
        for (int ks = 0; ks < 2; ++ks)
            wfrag[nt][ks] = wt[(nt * 2 + ks) * 64 + lane];

    const float4* bwt = (const float4*)(ws + 8192);
    float4 bw[8];                         // bw[ii] = {b1,Ws} for i=2ii, 2ii+1
    #pragma unroll
    for (int ii = 0; ii < 8; ++ii) bw[ii] = bwt[ii * 64 + lane];

    const int* ptab = (const int*)(ws + 16384);
    const float bsv = bs[0];

    // ones-row A fragment: A[0][k]=1 -> D[0][m] = sum_k B[k][m] = s_m
    const _Float16 onev = (l15 == 0) ? (_Float16)1.0f : (_Float16)0.0f;
    const f16x8 onesf = {onev, onev, onev, onev, onev, onev, onev, onev};

    __syncthreads();

    const char* xsb = (const char*)xs;
    const int qb = quad << 4;

    // ---- per-wave m-tiles of 16 pairs ----
    for (int t = wid; t < MT; t += 4) {
        const int p0 = t * 16;
        const int pk = ptab[p0 + l15];    // L2-hot global read
        const int io = ((unsigned)pk) >> 16;
        const int jo = pk & 0xFFFF;

        f16x8 xi0 = *(const f16x8*)(xsb + io + qb);        // k 0..31
        f16x8 xj0 = *(const f16x8*)(xsb + jo + qb);
        f16x8 xi1 = *(const f16x8*)(xsb + io + 64 + qb);   // k 32..63
        f16x8 xj1 = *(const f16x8*)(xsb + jo + 64 + qb);

        f16x8 A0 = xi0 * xj0;   // 4x v_pk_mul_f16
        f16x8 A1 = xi1 * xj1;

        f32x4 acc[NT];
        #pragma unroll
        for (int nt = 0; nt < NT; ++nt) { f32x4 z = {0.f,0.f,0.f,0.f}; acc[nt] = z; }
        f32x4 accs = {0.f, 0.f, 0.f, 0.f};

        // D = W1^T x cross -> h^T : row = n' = quad*4+reg, col = m = l15
        #pragma unroll
        for (int nt = 0; nt < NT; ++nt)
            acc[nt] = __builtin_amdgcn_mfma_f32_16x16x32_f16(wfrag[nt][0], A0, acc[nt], 0, 0, 0);
        accs = __builtin_amdgcn_mfma_f32_16x16x32_f16(onesf, A0, accs, 0, 0, 0);
        #pragma unroll
        for (int nt = 0; nt < NT; ++nt)
            acc[nt] = __builtin_amdgcn_mfma_f32_16x16x32_f16(wfrag[nt][1], A1, acc[nt], 0, 0, 0);
        accs = __builtin_amdgcn_mfma_f32_16x16x32_f16(onesf, A1, accs, 0, 0, 0);

        // in-lane partial: sum over n = nt*16+quad*4+reg of relu(h+b1)*Ws
        float s = 0.f;
        #pragma unroll
        for (int ii = 0; ii < 8; ++ii) {
            float v0 = acc[ii >> 1][(ii & 1) * 2] + bw[ii].x;
            v0 = v0 > 0.f ? v0 : 0.f;
            s = fmaf(v0, bw[ii].y, s);
            float v1 = acc[ii >> 1][(ii & 1) * 2 + 1] + bw[ii].z;
            v1 = v1 > 0.f ? v1 : 0.f;
            s = fmaf(v1, bw[ii].w, s);
        }
        // reduce across the 4 quads (same m = l15)
        s += __shfl_xor(s, 16, 64);
        s += __shfl_xor(s, 32, 64);
        if (quad == 0) {
            scores[p0 + l15] = s + bsv;
            svals[p0 + l15]  = accs[0];   // row 0 of ones-MFMA = s_m
        }
    }
    __syncthreads();

    // ---- softmax over 496 pairs; afm = sum attn*s ----
    float m = -1e30f;
    for (int p = tid; p < P; p += 256) m = fmaxf(m, scores[p]);
    #pragma unroll
    for (int off = 32; off >= 1; off >>= 1) m = fmaxf(m, __shfl_xor(m, off, 64));
    if (lane == 0) redmax[wid] = m;
    __syncthreads();
    m = fmaxf(fmaxf(redmax[0], redmax[1]), fmaxf(redmax[2], redmax[3]));

    float num = 0.f, den = 0.f;
    for (int p = tid; p < P; p += 256) {
        float e = __expf(scores[p] - m);
        num += e * svals[p];
        den += e;
    }
    #pragma unroll
    for (int off = 32; off >= 1; off >>= 1) {
        num += __shfl_xor(num, off, 64);
        den += __shfl_xor(den, off, 64);
    }
    if (lane == 0) { rednum[wid] = num; redden[wid] = den; }
    __syncthreads();
    if (tid == 0) {
        float nn = rednum[0] + rednum[1] + rednum[2] + rednum[3];
        float dd = redden[0] + redden[1] + redden[2] + redden[3];
        out[b] = nn / dd;
    }
}

extern "C" void kernel_launch(void* const* d_in, const int* in_sizes, int n_in,
                              void* d_out, int out_size, void* d_ws, size_t ws_size,
                              hipStream_t stream) {
    const float* x  = (const float*)d_in[0];
    const float* W1 = (const float*)d_in[1];
    const float* b1 = (const float*)d_in[2];
    const float* Ws = (const float*)d_in[3];
    const float* bs = (const float*)d_in[4];
    float* out = (float*)d_out;
    const int B = in_sizes[0] / (F * D);  // 2048
    prep_kernel<<<1, 256, 0, stream>>>(W1, b1, Ws, (char*)d_ws);
    afm_kernel<<<B, 256, 0, stream>>>(x, bs, (const char*)d_ws, out);
}